// Round 6
// baseline (140.584 us; speedup 1.0000x reference)
//
#include <hip/hip_runtime.h>

// CRF loss on MI355X — staggered 2-phase pipeline, 2 batches per wave.
// Round 6 = round 4 dataflow + issue-first GRADUATED lgkmcnt waits +
// __launch_bounds__(64,1) register headroom.
// B=512, L=512, T=32, S=34. Output f32[512].
//
// Per step, two slots (O: fwd FMA, E: bwd FMA). Slot structure:
//   publish (ds_write_b32) -> issue 8x ds_read_b128 (asm, untracked) ->
//   shadow (emission global-load + exp2) ->
//   lgkmcnt(15)/(13)/(11)/(9) graduated, interleaved with the 4 FMA pairs.
// DS completes FIFO per wave, so with outstanding = [Wprev, ra0..7, Wcur,
// rb0..7] = 18, "ra_k complete" == "outstanding <= 16-k": the k-th FMA pair
// waits only for its own operands while newer reads stay in flight (T4).
// Round 5's mistake (wait BEFORE issuing this slot's reads) serialized
// issue behind completion (+143 cy/step) — fixed here.
// __launch_bounds__(64,1): 1 wave/EU -> full VGPR budget (live set ~180;
// the default cap at ~90 forced AGPR/scratch shuffling on the FMA path).
// The 1/16-step rescale's ds_swizzle gets a compiler lgkmcnt(0) drain;
// at every placement this only completes ops early — correctness-safe.

typedef float f32x4 __attribute__((ext_vector_type(4)));

#define F2   1.4426950408889634f   // log2(e)
#define LN2  0.6931471805599453f
#define BIAS 0.0078125f            // 2^-7, exact
#define BIASCNT 3577               // 7 * 511 applications of biased tc

// 8x ds_read_b128 from one base address (offsets 0..112): 32-float
// broadcast read of one chain region (uniform addr per 32-lane half).
#define DS_RD8(r, a)                                                         \
  asm volatile("ds_read_b128 %0, %8 offset:0\n\t"                            \
               "ds_read_b128 %1, %8 offset:16\n\t"                           \
               "ds_read_b128 %2, %8 offset:32\n\t"                           \
               "ds_read_b128 %3, %8 offset:48\n\t"                           \
               "ds_read_b128 %4, %8 offset:64\n\t"                           \
               "ds_read_b128 %5, %8 offset:80\n\t"                           \
               "ds_read_b128 %6, %8 offset:96\n\t"                           \
               "ds_read_b128 %7, %8 offset:112"                              \
               : "=&v"((r)[0]), "=&v"((r)[1]), "=&v"((r)[2]), "=&v"((r)[3]), \
                 "=&v"((r)[4]), "=&v"((r)[5]), "=&v"((r)[6]), "=&v"((r)[7])  \
               : "v"(a))

#define DS_WR(a, x) asm volatile("ds_write_b32 %0, %1" :: "v"(a), "v"(x))

// counted wait + scheduling fence (guide rule 18: pin dependent VALU below)
#define LGKM(n) do { asm volatile("s_waitcnt lgkmcnt(" #n ")");              \
                     __builtin_amdgcn_sched_barrier(0); } while (0)

__device__ __forceinline__ float grpmax32(float x) {
    // max over each 32-lane half: 4 DPP row_ror fmax + ds_swizzle xor-16.
    int t;
    t = __builtin_amdgcn_update_dpp(__float_as_int(x), __float_as_int(x), 0x121, 0xf, 0xf, true);
    x = fmaxf(x, __int_as_float(t));   // row_ror:1
    t = __builtin_amdgcn_update_dpp(__float_as_int(x), __float_as_int(x), 0x122, 0xf, 0xf, true);
    x = fmaxf(x, __int_as_float(t));   // row_ror:2
    t = __builtin_amdgcn_update_dpp(__float_as_int(x), __float_as_int(x), 0x124, 0xf, 0xf, true);
    x = fmaxf(x, __int_as_float(t));   // row_ror:4
    t = __builtin_amdgcn_update_dpp(__float_as_int(x), __float_as_int(x), 0x128, 0xf, 0xf, true);
    x = fmaxf(x, __int_as_float(t));   // row_ror:8
    t = __builtin_amdgcn_ds_swizzle(__float_as_int(x), 0x401F);  // xor 16
    x = fmaxf(x, __int_as_float(t));
    return x;
}

__global__ __launch_bounds__(64, 1) void crf_kernel(
    const float* __restrict__ wtv,    // [512,512,32]
    const float* __restrict__ trans,  // [34,34]
    const int*   __restrict__ rtag,   // [512,512]
    float* __restrict__ out)          // [512]
{
    __shared__ __align__(16) float tlds[1156];  // raw translation (ln domain)
    __shared__ __align__(16) int   ltag[1024];  // gold tags, 2 batches
    __shared__ __align__(16) float alds[160];   // F: q*36+[0..31]; B: 80+q*36+[0..31]

    const int l = threadIdx.x;
    const int q = l >> 5;        // batch within pair
    const int c = l & 31;        // state-1
    const int bbase = blockIdx.x * 2;

    for (int k = l; k < 1156; k += 64) tlds[k] = trans[k];
    {
        const int* rtb = rtag + (size_t)bbase * 512;
        for (int k = l; k < 1024; k += 64) ltag[k] = rtb[k];
    }
    __syncthreads();  // once, before the main loop (graph-safe)

    // exp2-domain transitions, exact 2^-7 bias folded in
    float tcF[32], tcB[32];
    #pragma unroll
    for (int k = 0; k < 32; ++k) {
        tcF[k] = __builtin_exp2f(F2 * tlds[(k + 1) * 34 + (c + 1)]) * BIAS; // col c+1
        tcB[k] = __builtin_exp2f(F2 * tlds[(c + 1) * 34 + (k + 1)]) * BIAS; // row c+1
    }
    float aiF = __builtin_exp2f(F2 * tlds[c + 1]) * BIAS;  // START term, step 1 only

    const float* wbq = wtv + (size_t)(bbase + q) * (512 * 32);

    float stF = __builtin_exp2f(F2 * wbq[c]);   // alpha_0 (row-0 emission)
    float stB = 1.0f;                           // b_511
    int scF = 0, scB = 0;

    // emission pipeline: refilled 8 steps ahead inside the slot shadows
    float vnF[16], vnB[16];
    #pragma unroll
    for (int j = 0; j < 8; ++j) {
        vnF[j] = wbq[(1 + j) * 32 + c];        // rows 1..8
        vnB[j] = wbq[(511 - j) * 32 + c];      // rows 511..504
    }
    float eoF_c = __builtin_exp2f(F2 * vnF[0]);        // emission factor, step 1
    float gB    = stB * __builtin_exp2f(F2 * vnB[0]);  // bwd publish value, step 1

    // raw LDS byte addresses (low 32 bits of the flat shared address = LDS
    // offset on gfx9+)
    const unsigned abase  = (unsigned)(size_t)(void*)alds;
    const unsigned addrF  = abase + (unsigned)(q * 144);        // fwd region
    const unsigned addrB  = abase + 320u + (unsigned)(q * 144); // bwd region
    const unsigned addrFw = addrF + (unsigned)(c * 4);
    const unsigned addrBw = addrB + (unsigned)(c * 4);

    f32x4 ra_[8], rb_[8];

    // ---- prologue: publish alpha_0, issue fwd reads (outstanding = 9) ----
    DS_WR(addrFw, stF);
    DS_RD8(ra_, addrF);

    for (int t0 = 1; t0 <= 241; t0 += 16) {   // 16 bodies x 16 steps = i = 1..256
        #pragma unroll
        for (int j = 0; j < 16; ++j) {

            // ---- SLOT O: publish bwd g_i | issue bwd reads | shadow |
            //      graduated waits + fwd FMA step i ----
            DS_WR(addrBw, gB);                 // outstanding -> 10
            DS_RD8(rb_, addrB);                // outstanding -> 18
            vnB[(j + 8) & 15] = wbq[(512 - ((t0 + j) + 8)) * 32 + c];  // in-bounds at tail
            float eoB_n = __builtin_exp2f(F2 * vnB[(j + 1) & 15]);
            {
                float a0 = aiF, a1 = 0.0f, a2 = 0.0f, a3 = 0.0f;
                aiF = 0.0f;
                LGKM(15);                      // ra0,ra1 complete
                #pragma unroll
                for (int k = 0; k < 2; ++k) {
                    f32x4 x = ra_[k];
                    a0 += x[0] * tcF[4 * k + 0]; a1 += x[1] * tcF[4 * k + 1];
                    a2 += x[2] * tcF[4 * k + 2]; a3 += x[3] * tcF[4 * k + 3];
                }
                LGKM(13);                      // ra2,ra3
                #pragma unroll
                for (int k = 2; k < 4; ++k) {
                    f32x4 x = ra_[k];
                    a0 += x[0] * tcF[4 * k + 0]; a1 += x[1] * tcF[4 * k + 1];
                    a2 += x[2] * tcF[4 * k + 2]; a3 += x[3] * tcF[4 * k + 3];
                }
                LGKM(11);                      // ra4,ra5
                #pragma unroll
                for (int k = 4; k < 6; ++k) {
                    f32x4 x = ra_[k];
                    a0 += x[0] * tcF[4 * k + 0]; a1 += x[1] * tcF[4 * k + 1];
                    a2 += x[2] * tcF[4 * k + 2]; a3 += x[3] * tcF[4 * k + 3];
                }
                LGKM(9);                       // ra6,ra7
                #pragma unroll
                for (int k = 6; k < 8; ++k) {
                    f32x4 x = ra_[k];
                    a0 += x[0] * tcF[4 * k + 0]; a1 += x[1] * tcF[4 * k + 1];
                    a2 += x[2] * tcF[4 * k + 2]; a3 += x[3] * tcF[4 * k + 3];
                }
                float s = (a0 + a1) + (a2 + a3);
                stF = s * eoF_c;               // fwd updates at all i = 1..256
            }
            if (j == 15) {
                // fwd rescale (every 16 steps) between update and publish;
                // its ds_swizzle drains lgkm fully (1/16 steps, ops mostly done)
                float m = grpmax32(stF);
                int e = ((__float_as_int(m) >> 23) & 0xff) - 127;
                stF *= __int_as_float((127 - e) << 23);
                scF += e;
            }

            // ---- SLOT E: publish fwd alpha_i | issue fwd reads | shadow |
            //      graduated waits + bwd FMA step i ----
            DS_WR(addrFw, stF);
            DS_RD8(ra_, addrF);
            vnF[(j + 8) & 15] = wbq[((t0 + j) + 8) * 32 + c];          // in-bounds at tail
            float eoF_n = __builtin_exp2f(F2 * vnF[(j + 1) & 15]);
            {
                float a0 = 0.0f, a1 = 0.0f, a2 = 0.0f, a3 = 0.0f;
                LGKM(15);                      // rb0,rb1 complete
                #pragma unroll
                for (int k = 0; k < 2; ++k) {
                    f32x4 x = rb_[k];
                    a0 += x[0] * tcB[4 * k + 0]; a1 += x[1] * tcB[4 * k + 1];
                    a2 += x[2] * tcB[4 * k + 2]; a3 += x[3] * tcB[4 * k + 3];
                }
                LGKM(13);
                #pragma unroll
                for (int k = 2; k < 4; ++k) {
                    f32x4 x = rb_[k];
                    a0 += x[0] * tcB[4 * k + 0]; a1 += x[1] * tcB[4 * k + 1];
                    a2 += x[2] * tcB[4 * k + 2]; a3 += x[3] * tcB[4 * k + 3];
                }
                LGKM(11);
                #pragma unroll
                for (int k = 4; k < 6; ++k) {
                    f32x4 x = rb_[k];
                    a0 += x[0] * tcB[4 * k + 0]; a1 += x[1] * tcB[4 * k + 1];
                    a2 += x[2] * tcB[4 * k + 2]; a3 += x[3] * tcB[4 * k + 3];
                }
                LGKM(9);
                #pragma unroll
                for (int k = 6; k < 8; ++k) {
                    f32x4 x = rb_[k];
                    a0 += x[0] * tcB[4 * k + 0]; a1 += x[1] * tcB[4 * k + 1];
                    a2 += x[2] * tcB[4 * k + 2]; a3 += x[3] * tcB[4 * k + 3];
                }
                float s = (a0 + a1) + (a2 + a3);
                if (j == 15) stB = (t0 != 241) ? s : stB;  // i==256: fwd-only tail
                else         stB = s;
            }
            if (j == 15) {
                // bwd rescale at body end (before next publish)
                float m = grpmax32(stB);
                int e = ((__float_as_int(m) >> 23) & 0xff) - 127;
                stB *= __int_as_float((127 - e) << 23);
                scB += e;
            }
            gB    = stB * eoB_n;   // publish value for step i+1 (off write path)
            eoF_c = eoF_n;
        }
    }

    // drain our untracked asm DS ops before compiler-managed LDS traffic
    asm volatile("s_waitcnt lgkmcnt(0)");
    __builtin_amdgcn_sched_barrier(0);

    // ---- Z = sum_c af_256[c] * b_256[c], per 32-lane half ----
    float prod = stF * stB;
    prod += __shfl_xor(prod, 1);
    prod += __shfl_xor(prod, 2);
    prod += __shfl_xor(prod, 4);
    prod += __shfl_xor(prod, 8);
    prod += __shfl_xor(prod, 16);
    float total = ((float)(scF + scB + BIASCNT) + __builtin_log2f(prod)) * LN2;

    // ---- gold-path score epilogue: all 64 lanes per batch, gathers L2/L3-warm ----
    float ps0 = 0.0f, ps1 = 0.0f;
    #pragma unroll
    for (int bb = 0; bb < 2; ++bb) {
        const float* w  = wtv + (size_t)(bbase + bb) * (512 * 32);
        const int*   tg = ltag + (bb << 9);
        int   tcur[8];
        float em[8];
        #pragma unroll
        for (int k = 0; k < 8; ++k) tcur[k] = tg[l + 64 * k];
        #pragma unroll
        for (int k = 0; k < 8; ++k) em[k] = w[(l + 64 * k) * 32 + (tcur[k] - 1)];
        float acc = 0.0f;
        #pragma unroll
        for (int k = 0; k < 8; ++k) {
            int t  = l + 64 * k;
            int nx = tg[(t + 1) & 511];
            nx = (t == 511) ? 33 : nx;            // end term trans[tag_511][STOP]
            acc += em[k] + tlds[tcur[k] * 34 + nx];
        }
        if (l == 0) acc += tlds[tg[0]];           // start term trans[0][tag_0]
        acc += __shfl_xor(acc, 1);
        acc += __shfl_xor(acc, 2);
        acc += __shfl_xor(acc, 4);
        acc += __shfl_xor(acc, 8);
        acc += __shfl_xor(acc, 16);
        acc += __shfl_xor(acc, 32);
        if (bb == 0) ps0 = acc; else ps1 = acc;
    }
    float ps = (q == 0) ? ps0 : ps1;
    if (c == 0) out[bbase + q] = total - ps;      // lanes 0 and 32 write
}

extern "C" void kernel_launch(void* const* d_in, const int* in_sizes, int n_in,
                              void* d_out, int out_size, void* d_ws, size_t ws_size,
                              hipStream_t stream) {
    const float* wtv   = (const float*)d_in[0];
    const float* trans = (const float*)d_in[1];
    const int*   rtag  = (const int*)d_in[2];
    (void)in_sizes; (void)n_in; (void)d_ws; (void)ws_size; (void)out_size;
    float* out = (float*)d_out;
    crf_kernel<<<256, 64, 0, stream>>>(wtv, trans, rtag, out);
}

// Round 7
// 137.459 us; speedup vs baseline: 1.0227x; 1.0227x over previous
//
#include <hip/hip_runtime.h>

// CRF loss on MI355X — staggered 2-phase pipeline, 2 batches per wave.
// Round 7 = round 4 dataflow with ROTATED slot bodies: FMA first, then
// update -> publish -> read-issue -> shadow at the slot END, so each 8-read
// LDS burst is issued a full slot (+shadow) before its first consumption
// (~135-165 cy margin vs R4's ~100-130 against ~150 cy b128-broadcast
// latency). Same operations, same numerics as R4 (verified absmax 0.0).
// B=512, L=512, T=32, S=34. Output f32[512].
//
// Riders: (a) rescale xor-16 via v_permlane16_swap_b32 (gfx950 VALU
// cross-lane; removes the mid-loop lgkmcnt(0) drain ds_swizzle forced,
// which landed right after the freshly-issued reads); (b)
// __launch_bounds__(64,1) — cap non-binding at VGPR~88, removes doubt.
// No asm DS ops (R5/R6 lesson: the compiler's own ds_read/waitcnt/FMA
// interleave + register reuse beats hand-pinned asm here).

#define F2   1.4426950408889634f   // log2(e)
#define LN2  0.6931471805599453f
#define BIAS 0.0078125f            // 2^-7, exact
#define BIASCNT 3577               // 7 * 511 applications of biased tc

__device__ __forceinline__ float grpmax32(float x) {
    // max over each 32-lane half: 4 DPP row_ror fmax (16-lane rows) +
    // v_permlane16_swap_b32 for the xor-16 exchange (pure VALU, no lgkm).
    int t;
    t = __builtin_amdgcn_update_dpp(__float_as_int(x), __float_as_int(x), 0x121, 0xf, 0xf, true);
    x = fmaxf(x, __int_as_float(t));   // row_ror:1
    t = __builtin_amdgcn_update_dpp(__float_as_int(x), __float_as_int(x), 0x122, 0xf, 0xf, true);
    x = fmaxf(x, __int_as_float(t));   // row_ror:2
    t = __builtin_amdgcn_update_dpp(__float_as_int(x), __float_as_int(x), 0x124, 0xf, 0xf, true);
    x = fmaxf(x, __int_as_float(t));   // row_ror:4
    t = __builtin_amdgcn_update_dpp(__float_as_int(x), __float_as_int(x), 0x128, 0xf, 0xf, true);
    x = fmaxf(x, __int_as_float(t));   // row_ror:8 -> per-16-row max
    // xor-16: swap odd 16-rows of a with even 16-rows of b (a=b=x), then max.
    int a = __float_as_int(x), b = __float_as_int(x);
    asm("v_permlane16_swap_b32 %0, %1" : "+v"(a), "+v"(b));
    x = fmaxf(__int_as_float(a), __int_as_float(b));
    return x;
}

__global__ __launch_bounds__(64, 1) void crf_kernel(
    const float* __restrict__ wtv,    // [512,512,32]
    const float* __restrict__ trans,  // [34,34]
    const int*   __restrict__ rtag,   // [512,512]
    float* __restrict__ out)          // [512]
{
    __shared__ __align__(16) float tlds[1156];  // raw translation (ln domain)
    __shared__ __align__(16) int   ltag[1024];  // gold tags, 2 batches
    __shared__ __align__(16) float alds[160];   // F: q*36+[0..31]; B: 80+q*36+[0..31]

    const int l = threadIdx.x;
    const int q = l >> 5;        // batch within pair
    const int c = l & 31;        // state-1
    const int bbase = blockIdx.x * 2;

    for (int k = l; k < 1156; k += 64) tlds[k] = trans[k];
    {
        const int* rtb = rtag + (size_t)bbase * 512;
        for (int k = l; k < 1024; k += 64) ltag[k] = rtb[k];
    }
    __syncthreads();  // once, before the main loop (graph-safe)

    // exp2-domain transitions, exact 2^-7 bias folded in
    float tcF[32], tcB[32];
    #pragma unroll
    for (int k = 0; k < 32; ++k) {
        tcF[k] = __builtin_exp2f(F2 * tlds[(k + 1) * 34 + (c + 1)]) * BIAS; // col c+1
        tcB[k] = __builtin_exp2f(F2 * tlds[(c + 1) * 34 + (k + 1)]) * BIAS; // row c+1
    }
    float aiF = __builtin_exp2f(F2 * tlds[c + 1]) * BIAS;  // START term, step 1 only

    const float* wbq = wtv + (size_t)(bbase + q) * (512 * 32);

    float stF = __builtin_exp2f(F2 * wbq[c]);   // alpha_0 (row-0 emission)
    float stB = 1.0f;                           // b_511
    int scF = 0, scB = 0;

    // emission pipeline: refilled 8 steps ahead inside the slot shadows
    float vnF[16], vnB[16];
    #pragma unroll
    for (int j = 0; j < 8; ++j) {
        vnF[j] = wbq[(1 + j) * 32 + c];        // rows 1..8
        vnB[j] = wbq[(511 - j) * 32 + c];      // rows 511..504
    }
    float eoF_c = __builtin_exp2f(F2 * vnF[0]);        // emission factor, step 1
    float gB    = stB * __builtin_exp2f(F2 * vnB[0]);  // g_1 = b_511 * eo(row 511)

    float* aF = alds + q * 36;          // fwd region (16B-aligned, +4 banks/half)
    float* aB = alds + 80 + q * 36;     // bwd region
    const float4* f4 = (const float4*)aF;
    const float4* b4 = (const float4*)aB;

    float4 ra[8], rb[8];

    // ---- prologue: publish alpha_0 AND g_1, issue both read bursts ----
    aF[c] = stF;
    aB[c] = gB;
    __builtin_amdgcn_wave_barrier();
    #pragma unroll
    for (int k = 0; k < 8; ++k) ra[k] = f4[k];
    #pragma unroll
    for (int k = 0; k < 8; ++k) rb[k] = b4[k];
    __builtin_amdgcn_wave_barrier();

    for (int t0 = 1; t0 <= 241; t0 += 16) {   // 16 bodies x 16 steps = i = 1..256
        #pragma unroll
        for (int j = 0; j < 16; ++j) {
            const int i = t0 + j;

            // ---- SLOT O: fwd FMA step i (ra issued end of prev slot O) |
            //      update -> [rescale] -> publish alpha_i -> issue ra' -> shadow ----
            {
                float a0 = aiF, a1 = 0.0f, a2 = 0.0f, a3 = 0.0f;
                aiF = 0.0f;
                #pragma unroll
                for (int k = 0; k < 8; ++k) {
                    float4 x = ra[k];
                    a0 += x.x * tcF[4 * k + 0]; a1 += x.y * tcF[4 * k + 1];
                    a2 += x.z * tcF[4 * k + 2]; a3 += x.w * tcF[4 * k + 3];
                }
                float s = (a0 + a1) + (a2 + a3);
                stF = s * eoF_c;               // fwd updates at all i = 1..256
            }
            if (j == 15) {
                // fwd rescale (every 16 steps) between update and publish
                float m = grpmax32(stF);
                int e = ((__float_as_int(m) >> 23) & 0xff) - 127;
                stF *= __int_as_float((127 - e) << 23);
                scF += e;
            }
            aF[c] = stF;
            __builtin_amdgcn_wave_barrier();
            #pragma unroll
            for (int k = 0; k < 8; ++k) ra[k] = f4[k];   // ra for step i+1
            __builtin_amdgcn_wave_barrier();
            // shadow: bwd emission prefetch (tail rows >= 248: in-bounds) +
            // next bwd emission factor (for g_{i+1}, consumed in slot E)
            vnB[(j + 8) & 15] = wbq[(512 - (i + 8)) * 32 + c];
            float eoB_n = __builtin_exp2f(F2 * vnB[(j + 1) & 15]);

            // ---- SLOT E: bwd FMA step i (rb issued end of prev slot E) |
            //      update -> [rescale] -> publish g_{i+1} -> issue rb' -> shadow ----
            {
                float a0 = 0.0f, a1 = 0.0f, a2 = 0.0f, a3 = 0.0f;
                #pragma unroll
                for (int k = 0; k < 8; ++k) {
                    float4 x = rb[k];
                    a0 += x.x * tcB[4 * k + 0]; a1 += x.y * tcB[4 * k + 1];
                    a2 += x.z * tcB[4 * k + 2]; a3 += x.w * tcB[4 * k + 3];
                }
                float s = (a0 + a1) + (a2 + a3);
                if (j == 15) stB = (t0 != 241) ? s : stB;  // i==256: fwd-only tail
                else         stB = s;
            }
            if (j == 15) {
                // bwd rescale at body end (before next publish)
                float m = grpmax32(stB);
                int e = ((__float_as_int(m) >> 23) & 0xff) - 127;
                stB *= __int_as_float((127 - e) << 23);
                scB += e;
            }
            gB = stB * eoB_n;                  // g_{i+1}
            aB[c] = gB;
            __builtin_amdgcn_wave_barrier();
            #pragma unroll
            for (int k = 0; k < 8; ++k) rb[k] = b4[k];   // rb for step i+1
            __builtin_amdgcn_wave_barrier();
            // shadow: fwd emission prefetch (tail rows <= 264: in-bounds) +
            // next fwd emission factor (consumed in next slot O)
            vnF[(j + 8) & 15] = wbq[(i + 8) * 32 + c];
            eoF_c = __builtin_exp2f(F2 * vnF[(j + 1) & 15]);
        }
    }

    // ---- Z = sum_c af_256[c] * b_256[c], per 32-lane half ----
    float prod = stF * stB;
    prod += __shfl_xor(prod, 1);
    prod += __shfl_xor(prod, 2);
    prod += __shfl_xor(prod, 4);
    prod += __shfl_xor(prod, 8);
    prod += __shfl_xor(prod, 16);
    float total = ((float)(scF + scB + BIASCNT) + __builtin_log2f(prod)) * LN2;

    // ---- gold-path score epilogue: all 64 lanes per batch, gathers L2/L3-warm ----
    float ps0 = 0.0f, ps1 = 0.0f;
    #pragma unroll
    for (int bb = 0; bb < 2; ++bb) {
        const float* w  = wtv + (size_t)(bbase + bb) * (512 * 32);
        const int*   tg = ltag + (bb << 9);
        int   tcur[8];
        float em[8];
        #pragma unroll
        for (int k = 0; k < 8; ++k) tcur[k] = tg[l + 64 * k];
        #pragma unroll
        for (int k = 0; k < 8; ++k) em[k] = w[(l + 64 * k) * 32 + (tcur[k] - 1)];
        float acc = 0.0f;
        #pragma unroll
        for (int k = 0; k < 8; ++k) {
            int t  = l + 64 * k;
            int nx = tg[(t + 1) & 511];
            nx = (t == 511) ? 33 : nx;            // end term trans[tag_511][STOP]
            acc += em[k] + tlds[tcur[k] * 34 + nx];
        }
        if (l == 0) acc += tlds[tg[0]];           // start term trans[0][tag_0]
        acc += __shfl_xor(acc, 1);
        acc += __shfl_xor(acc, 2);
        acc += __shfl_xor(acc, 4);
        acc += __shfl_xor(acc, 8);
        acc += __shfl_xor(acc, 16);
        acc += __shfl_xor(acc, 32);
        if (bb == 0) ps0 = acc; else ps1 = acc;
    }
    float ps = (q == 0) ? ps0 : ps1;
    if (c == 0) out[bbase + q] = total - ps;      // lanes 0 and 32 write
}

extern "C" void kernel_launch(void* const* d_in, const int* in_sizes, int n_in,
                              void* d_out, int out_size, void* d_ws, size_t ws_size,
                              hipStream_t stream) {
    const float* wtv   = (const float*)d_in[0];
    const float* trans = (const float*)d_in[1];
    const int*   rtag  = (const int*)d_in[2];
    (void)in_sizes; (void)n_in; (void)d_ws; (void)ws_size; (void)out_size;
    float* out = (float*)d_out;
    crf_kernel<<<256, 64, 0, stream>>>(wtv, trans, rtag, out);
}

// Round 8
// 137.270 us; speedup vs baseline: 1.0241x; 1.0014x over previous
//
#include <hip/hip_runtime.h>

// CRF loss on MI355X — staggered 2-phase pipeline, 2 batches per wave.
// Round 8 = round 4 (verified absmax 0.0) with the dot-product FMAs packed
// as v_pk_fma_f32 (2 FLOPs/lane/instr): 64 -> 32 FMA instructions/step.
// B=512, L=512, T=32, S=34. Output f32[512].
//
// R7's null result (rotating read-issue a full slot earlier changed
// nothing) showed the residual per-step cost is FMA *issue*, not exposed
// LDS latency — so halve the issue. Accumulator pairing (a0,a1)/(a2,a3)
// keeps the arithmetic bit-exact vs R4. __builtin_elementwise_fma on
// ext_vector float2 guarantees llvm.fma.v2f32 -> v_pk_fma_f32 on gfx950.
// grpmax32 reverted to the verified DPP+ds_swizzle form (R7's
// v_permlane16_swap broke: "+v"(a),"+v"(b) with a==b lets the RA coalesce
// them into one register, making the swap in-place -> non-uniform rescale
// exponent within a chain -> absmax 16).

typedef float f32x2 __attribute__((ext_vector_type(2)));

#define F2   1.4426950408889634f   // log2(e)
#define LN2  0.6931471805599453f
#define BIAS 0.0078125f            // 2^-7, exact
#define BIASCNT 3577               // 7 * 511 applications of biased tc

__device__ __forceinline__ float grpmax32(float x) {
    // max over each 32-lane half: 4 DPP row_ror fmax + ds_swizzle xor-16.
    // (verified absmax 0.0 in rounds 4-6)
    int t;
    t = __builtin_amdgcn_update_dpp(__float_as_int(x), __float_as_int(x), 0x121, 0xf, 0xf, true);
    x = fmaxf(x, __int_as_float(t));   // row_ror:1
    t = __builtin_amdgcn_update_dpp(__float_as_int(x), __float_as_int(x), 0x122, 0xf, 0xf, true);
    x = fmaxf(x, __int_as_float(t));   // row_ror:2
    t = __builtin_amdgcn_update_dpp(__float_as_int(x), __float_as_int(x), 0x124, 0xf, 0xf, true);
    x = fmaxf(x, __int_as_float(t));   // row_ror:4
    t = __builtin_amdgcn_update_dpp(__float_as_int(x), __float_as_int(x), 0x128, 0xf, 0xf, true);
    x = fmaxf(x, __int_as_float(t));   // row_ror:8 -> per-16-row max
    t = __builtin_amdgcn_ds_swizzle(__float_as_int(x), 0x401F);  // xor 16
    x = fmaxf(x, __int_as_float(t));
    return x;
}

__global__ __launch_bounds__(64, 1) void crf_kernel(
    const float* __restrict__ wtv,    // [512,512,32]
    const float* __restrict__ trans,  // [34,34]
    const int*   __restrict__ rtag,   // [512,512]
    float* __restrict__ out)          // [512]
{
    __shared__ __align__(16) float tlds[1156];  // raw translation (ln domain)
    __shared__ __align__(16) int   ltag[1024];  // gold tags, 2 batches
    __shared__ __align__(16) float alds[160];   // F: q*36+[0..31]; B: 80+q*36+[0..31]

    const int l = threadIdx.x;
    const int q = l >> 5;        // batch within pair
    const int c = l & 31;        // state-1
    const int bbase = blockIdx.x * 2;

    for (int k = l; k < 1156; k += 64) tlds[k] = trans[k];
    {
        const int* rtb = rtag + (size_t)bbase * 512;
        for (int k = l; k < 1024; k += 64) ltag[k] = rtb[k];
    }
    __syncthreads();  // once, before the main loop (graph-safe)

    // exp2-domain transitions, exact 2^-7 bias folded in, packed in pairs:
    // tc2F[2k] = {tcF[4k], tcF[4k+1]}, tc2F[2k+1] = {tcF[4k+2], tcF[4k+3]}
    f32x2 tc2F[16], tc2B[16];
    #pragma unroll
    for (int k = 0; k < 16; ++k) {
        f32x2 vF, vB;
        vF.x = __builtin_exp2f(F2 * tlds[(2 * k + 1) * 34 + (c + 1)]) * BIAS;
        vF.y = __builtin_exp2f(F2 * tlds[(2 * k + 2) * 34 + (c + 1)]) * BIAS;
        vB.x = __builtin_exp2f(F2 * tlds[(c + 1) * 34 + (2 * k + 1)]) * BIAS;
        vB.y = __builtin_exp2f(F2 * tlds[(c + 1) * 34 + (2 * k + 2)]) * BIAS;
        tc2F[k] = vF;
        tc2B[k] = vB;
    }
    float aiF = __builtin_exp2f(F2 * tlds[c + 1]) * BIAS;  // START term, step 1 only

    const float* wbq = wtv + (size_t)(bbase + q) * (512 * 32);

    float stF = __builtin_exp2f(F2 * wbq[c]);   // alpha_0 (row-0 emission)
    float stB = 1.0f;                           // b_511
    int scF = 0, scB = 0;

    // emission pipeline: refilled 8 steps ahead inside the slot shadows
    float vnF[16], vnB[16];
    #pragma unroll
    for (int j = 0; j < 8; ++j) {
        vnF[j] = wbq[(1 + j) * 32 + c];        // rows 1..8
        vnB[j] = wbq[(511 - j) * 32 + c];      // rows 511..504
    }
    float eoF_c = __builtin_exp2f(F2 * vnF[0]);        // emission factor, step 1
    float gB    = stB * __builtin_exp2f(F2 * vnB[0]);  // bwd publish value, step 1

    float* aF = alds + q * 36;          // fwd region (16B-aligned, +4 banks/half)
    float* aB = alds + 80 + q * 36;     // bwd region
    const float4* f4 = (const float4*)aF;
    const float4* b4 = (const float4*)aB;

    float4 ra[8], rb[8];

    // ---- prologue: publish alpha_0, issue fwd reads ----
    aF[c] = stF;
    __builtin_amdgcn_wave_barrier();
    #pragma unroll
    for (int k = 0; k < 8; ++k) ra[k] = f4[k];
    __builtin_amdgcn_wave_barrier();

    for (int t0 = 1; t0 <= 241; t0 += 16) {   // 16 bodies x 16 steps = i = 1..256
        #pragma unroll
        for (int j = 0; j < 16; ++j) {
            const int i = t0 + j;

            // ---- SLOT O: publish bwd g_i, issue bwd reads | shadow |
            //      fwd pk-FMA step i ----
            aB[c] = gB;
            __builtin_amdgcn_wave_barrier();
            #pragma unroll
            for (int k = 0; k < 8; ++k) rb[k] = b4[k];
            __builtin_amdgcn_wave_barrier();
            // shadow: bwd emission prefetch (tail rows >= 248: in-bounds) +
            // next-step bwd emission factor
            vnB[(j + 8) & 15] = wbq[(512 - (i + 8)) * 32 + c];
            float eoB_n = __builtin_exp2f(F2 * vnB[(j + 1) & 15]);
            {
                f32x2 a01 = {aiF, 0.0f};
                f32x2 a23 = {0.0f, 0.0f};
                aiF = 0.0f;
                #pragma unroll
                for (int k = 0; k < 8; ++k) {
                    float4 x = ra[k];
                    f32x2 xlo = {x.x, x.y};
                    f32x2 xhi = {x.z, x.w};
                    a01 = __builtin_elementwise_fma(xlo, tc2F[2 * k + 0], a01);
                    a23 = __builtin_elementwise_fma(xhi, tc2F[2 * k + 1], a23);
                }
                float s = (a01.x + a01.y) + (a23.x + a23.y);
                stF = s * eoF_c;               // fwd updates at all i = 1..256
            }
            if (j == 15) {
                // fwd rescale (every 16 steps) between update and publish
                float m = grpmax32(stF);
                int e = ((__float_as_int(m) >> 23) & 0xff) - 127;
                stF *= __int_as_float((127 - e) << 23);
                scF += e;
            }

            // ---- SLOT E: publish fwd alpha_i, issue fwd reads | shadow |
            //      bwd pk-FMA step i ----
            aF[c] = stF;
            __builtin_amdgcn_wave_barrier();
            #pragma unroll
            for (int k = 0; k < 8; ++k) ra[k] = f4[k];
            __builtin_amdgcn_wave_barrier();
            // shadow: fwd emission prefetch (tail rows <= 264: in-bounds) +
            // next-step fwd emission factor
            vnF[(j + 8) & 15] = wbq[(i + 8) * 32 + c];
            float eoF_n = __builtin_exp2f(F2 * vnF[(j + 1) & 15]);
            {
                f32x2 a01 = {0.0f, 0.0f};
                f32x2 a23 = {0.0f, 0.0f};
                #pragma unroll
                for (int k = 0; k < 8; ++k) {
                    float4 x = rb[k];
                    f32x2 xlo = {x.x, x.y};
                    f32x2 xhi = {x.z, x.w};
                    a01 = __builtin_elementwise_fma(xlo, tc2B[2 * k + 0], a01);
                    a23 = __builtin_elementwise_fma(xhi, tc2B[2 * k + 1], a23);
                }
                float s = (a01.x + a01.y) + (a23.x + a23.y);
                if (j == 15) stB = (t0 != 241) ? s : stB;  // i==256: fwd-only tail
                else         stB = s;
            }
            if (j == 15) {
                // bwd rescale at body end (before next publish)
                float m = grpmax32(stB);
                int e = ((__float_as_int(m) >> 23) & 0xff) - 127;
                stB *= __int_as_float((127 - e) << 23);
                scB += e;
            }
            gB    = stB * eoB_n;   // publish value for step i+1 (off write path)
            eoF_c = eoF_n;
        }
    }

    // ---- Z = sum_c af_256[c] * b_256[c], per 32-lane half ----
    float prod = stF * stB;
    prod += __shfl_xor(prod, 1);
    prod += __shfl_xor(prod, 2);
    prod += __shfl_xor(prod, 4);
    prod += __shfl_xor(prod, 8);
    prod += __shfl_xor(prod, 16);
    float total = ((float)(scF + scB + BIASCNT) + __builtin_log2f(prod)) * LN2;

    // ---- gold-path score epilogue: all 64 lanes per batch, gathers L2/L3-warm ----
    float ps0 = 0.0f, ps1 = 0.0f;
    #pragma unroll
    for (int bb = 0; bb < 2; ++bb) {
        const float* w  = wtv + (size_t)(bbase + bb) * (512 * 32);
        const int*   tg = ltag + (bb << 9);
        int   tcur[8];
        float em[8];
        #pragma unroll
        for (int k = 0; k < 8; ++k) tcur[k] = tg[l + 64 * k];
        #pragma unroll
        for (int k = 0; k < 8; ++k) em[k] = w[(l + 64 * k) * 32 + (tcur[k] - 1)];
        float acc = 0.0f;
        #pragma unroll
        for (int k = 0; k < 8; ++k) {
            int t  = l + 64 * k;
            int nx = tg[(t + 1) & 511];
            nx = (t == 511) ? 33 : nx;            // end term trans[tag_511][STOP]
            acc += em[k] + tlds[tcur[k] * 34 + nx];
        }
        if (l == 0) acc += tlds[tg[0]];           // start term trans[0][tag_0]
        acc += __shfl_xor(acc, 1);
        acc += __shfl_xor(acc, 2);
        acc += __shfl_xor(acc, 4);
        acc += __shfl_xor(acc, 8);
        acc += __shfl_xor(acc, 16);
        acc += __shfl_xor(acc, 32);
        if (bb == 0) ps0 = acc; else ps1 = acc;
    }
    float ps = (q == 0) ? ps0 : ps1;
    if (c == 0) out[bbase + q] = total - ps;      // lanes 0 and 32 write
}

extern "C" void kernel_launch(void* const* d_in, const int* in_sizes, int n_in,
                              void* d_out, int out_size, void* d_ws, size_t ws_size,
                              hipStream_t stream) {
    const float* wtv   = (const float*)d_in[0];
    const float* trans = (const float*)d_in[1];
    const int*   rtag  = (const int*)d_in[2];
    (void)in_sizes; (void)n_in; (void)d_ws; (void)ws_size; (void)out_size;
    float* out = (float*)d_out;
    crf_kernel<<<256, 64, 0, stream>>>(wtv, trans, rtag, out);
}